// Round 1
// baseline (181.085 us; speedup 1.0000x reference)
//
#include <hip/hip_runtime.h>

typedef unsigned short u16;
typedef unsigned int   u32;
typedef __bf16 bf16x8 __attribute__((ext_vector_type(8)));
typedef float  f32x4  __attribute__((ext_vector_type(4)));
typedef float  f32x16 __attribute__((ext_vector_type(16)));

#define TSEQ 2048
#define NHEAD 16
#define HDIM 64
#define CDIM 1024
#define N3   3072
#define MROWS 4096

__device__ __forceinline__ u16 f2bf(float f) {
    union { float f; u32 u; } v; v.f = f;
    u32 r = v.u + 0x7FFFu + ((v.u >> 16) & 1u);
    return (u16)(r >> 16);
}

// pack two fp32 -> packed bf16, 1-2 VALU ops.
__device__ __forceinline__ u32 pkbf(float a, float b) {
#if __has_builtin(__builtin_amdgcn_cvt_pk_bf16_f32)
    typedef __bf16 bf16x2 __attribute__((ext_vector_type(2)));
    bf16x2 t = __builtin_amdgcn_cvt_pk_bf16_f32(a, b);
    union { bf16x2 v; u32 u; } c; c.v = t; return c.u;
#else
    union { float f; u32 u; } ua, ub; ua.f = a; ub.f = b;
    u32 sel = 0x07060302, d;
    asm("v_perm_b32 %0, %1, %2, %3" : "=v"(d) : "v"(ub.u), "v"(ua.u), "v"(sel));
    return d;
#endif
}

// async global->LDS, 16B per lane (m97; GEMM staging only)
__device__ __forceinline__ void gld16(const u16* g, u16* l) {
    __builtin_amdgcn_global_load_lds(
        (const __attribute__((address_space(1))) u32*)g,
        (__attribute__((address_space(3))) u32*)l, 16, 0, 0);
}

// ---------------- merged prep: x->bf16 pack  +  both weight transposes ----------------
__global__ __launch_bounds__(256) void prep_kernel(const float* __restrict__ x,
                                                   const float* __restrict__ wqkv,
                                                   const float* __restrict__ wproj,
                                                   u16* __restrict__ Xb,
                                                   u16* __restrict__ oqkv, u16* __restrict__ oproj) {
    __shared__ float tile[32][33];
    const int bx = blockIdx.x;
    const int tid = threadIdx.x;
    if (bx < 4096) {  // pack region
        int i = bx * 256 + tid;
        float4 v = reinterpret_cast<const float4*>(x)[i];
        ushort4 o;
        o.x = f2bf(v.x); o.y = f2bf(v.y); o.z = f2bf(v.z); o.w = f2bf(v.w);
        reinterpret_cast<ushort4*>(Xb)[i] = o;
        return;
    }
    int idx = bx - 4096;
    int bnx = idx & 127;
    int k0  = (idx >> 7) * 32;
    const float* in; u16* out; int N, n0;
    if (bnx < 96) { in = wqkv;  out = oqkv;  N = 3072; n0 = bnx * 32; }
    else          { in = wproj; out = oproj; N = 1024; n0 = (bnx - 96) * 32; }
    int tx = tid & 31, ty = tid >> 5;  // (32, 8)
#pragma unroll
    for (int i = 0; i < 4; i++)
        tile[ty + i * 8][tx] = in[(size_t)(k0 + ty + i * 8) * N + n0 + tx];
    __syncthreads();
#pragma unroll
    for (int i = 0; i < 4; i++)
        out[(size_t)(n0 + ty + i * 8) * 1024 + k0 + tx] = f2bf(tile[tx][ty + i * 8]);
}

// ---------------- QKV GEMM: frag-order epilogue via LDS bounce (verified rounds 7/8) ----------------
// Qf chunk ((bh*64+qt)*4+kc): [lane=l5*32+q31][j] = Q[qt*32+q31][kc*16+l5*8+j]*c2
// Kf tile (bh*32+kb), chunk kc*2+nt: [lane][j] = K[nt*32+l31][kc*16+l5*8+j]
// Vf tile (bh*32+kb), chunk c*2+dt:  [lane][j] = V[c*16+(j>>2)*8+l5*4+(j&3)][dt*32+l31]
__global__ __launch_bounds__(256) void gemm_qkv(const u16* __restrict__ A, const u16* __restrict__ Bt,
                                                const float* __restrict__ bias, u16* __restrict__ Qf,
                                                u16* __restrict__ Kf, u16* __restrict__ Vf) {
    __shared__ __align__(16) u16 Al[128 * 32];
    __shared__ __align__(16) u16 Bl[128 * 32];
    __shared__ __align__(16) u16 Im[16384];
    const int tid  = threadIdx.x;
    const int lane = tid & 63;
    const int wave = tid >> 6;
    const int wm = (wave >> 1) * 64;
    const int wn = (wave & 1) * 64;
    const int row0 = blockIdx.x * 128;
    const int col0 = blockIdx.y * 128;
    const int lr = lane & 15;
    const int lq = lane >> 4;
    const float c2 = 0.125f * 1.44269504088896f;

    f32x4 acc[4][4];
#pragma unroll
    for (int i = 0; i < 4; i++)
#pragma unroll
        for (int j = 0; j < 4; j++) acc[i][j] = f32x4{0.f, 0.f, 0.f, 0.f};

    const int sr = tid >> 2, sc_ = (tid & 3) * 8;

    for (int k0 = 0; k0 < CDIM; k0 += 32) {
#pragma unroll
        for (int s = 0; s < 2; s++) {
            int i = tid + s * 256;
            int r = sr + s * 64;
            gld16(&A[(size_t)(row0 + r) * CDIM + k0 + sc_], &Al[i * 8]);
            gld16(&Bt[(size_t)(col0 + r) * CDIM + k0 + sc_], &Bl[i * 8]);
        }
        __syncthreads();
        bf16x8 af[4], bfr[4];
#pragma unroll
        for (int t = 0; t < 4; t++) {
            af[t]  = *reinterpret_cast<const bf16x8*>(&Al[(wm + t * 16 + lr) * 32 + lq * 8]);
            bfr[t] = *reinterpret_cast<const bf16x8*>(&Bl[(wn + t * 16 + lr) * 32 + lq * 8]);
        }
#pragma unroll
        for (int mt = 0; mt < 4; mt++)
#pragma unroll
            for (int nt = 0; nt < 4; nt++)
                acc[mt][nt] = __builtin_amdgcn_mfma_f32_16x16x32_bf16(af[mt], bfr[nt], acc[mt][nt], 0, 0, 0);
        __syncthreads();
    }

    const int region = col0 >> 10;
    const int h_base = (col0 & 1023) >> 6;
#pragma unroll
    for (int mt = 0; mt < 4; mt++) {
#pragma unroll
        for (int nt = 0; nt < 4; nt++) {
            int n_local = wn + nt * 16 + lr;
            float bv = bias[col0 + n_local];
            int h_local = n_local >> 6;
            int d = n_local & 63;
#pragma unroll
            for (int r = 0; r < 4; r++) {
                int m_local = wm + mt * 16 + lq * 4 + r;
                float v = acc[mt][nt][r] + bv;
                if (region == 0) {
                    int qt_local = m_local >> 5, q31 = m_local & 31;
                    int kc = d >> 4, l5b = (d >> 3) & 1, j = d & 7;
                    int lc = (h_local * 4 + qt_local) * 4 + kc;
                    Im[lc * 512 + (l5b * 32 + q31) * 8 + j] = f2bf(v * c2);
                } else if (region == 1) {
                    int kb_local = m_local >> 6, tr = m_local & 63;
                    int kc = d >> 4, l5b = (d >> 3) & 1, j = d & 7;
                    int nt2 = tr >> 5, p31 = tr & 31;
                    int lc = (h_local * 2 + kb_local) * 8 + kc * 2 + nt2;
                    Im[lc * 512 + (l5b * 32 + p31) * 8 + j] = f2bf(v);
                } else {
                    int kb_local = m_local >> 6, tr = m_local & 63;
                    int cV = tr >> 4, dt2 = d >> 5, p31 = d & 31;
                    int l5b = (tr >> 2) & 1;
                    int j = ((tr >> 3) & 1) * 4 + (tr & 3);
                    int lc = (h_local * 2 + kb_local) * 8 + cV * 2 + dt2;
                    Im[lc * 512 + (l5b * 32 + p31) * 8 + j] = f2bf(v);
                }
            }
        }
    }
    __syncthreads();
    const int bq = row0 >> 11;
    const int qrow0 = row0 & 2047;
#pragma unroll
    for (int s = 0; s < 8; s++) {
        int slot = s * 256 + tid;
        int lc = slot >> 6, li = slot & 63;
        uint4 data = *reinterpret_cast<const uint4*>(&Im[slot * 8]);
        if (region == 0) {
            int h_local = lc >> 4, qt_local = (lc >> 2) & 3, kc = lc & 3;
            size_t off = ((size_t)((bq * 16 + h_base + h_local) * 64 + (qrow0 >> 5) + qt_local) * 4 + kc) * 512
                       + li * 8;
            *reinterpret_cast<uint4*>(Qf + off) = data;
        } else {
            int h_local = lc >> 4, kb_local = (lc >> 3) & 1, cit = lc & 7;
            size_t off = (size_t)((bq * 16 + h_base + h_local) * 32 + (qrow0 >> 6) + kb_local) * 4096
                       + cit * 512 + li * 8;
            *reinterpret_cast<uint4*>((region == 1 ? Kf : Vf) + off) = data;
        }
    }
}

// ---------------- proj GEMM: 64x128 tile, BK=64 (2x BK=32 sub-tiles), fp32 out ----------------
__global__ __launch_bounds__(256) void gemm_proj(const u16* __restrict__ A, const u16* __restrict__ Bt,
                                                 const float* __restrict__ bias, float* __restrict__ C) {
    __shared__ __align__(16) u16 Al[2 * 64 * 32];    // [kk][64][32]
    __shared__ __align__(16) u16 Bl[2 * 128 * 32];   // [kk][128][32]
    const int tid  = threadIdx.x;
    const int lane = tid & 63;
    const int wave = tid >> 6;
    const int wm = (wave >> 1) * 32;
    const int wn = (wave & 1) * 64;
    const int row0 = blockIdx.x * 64;
    const int col0 = blockIdx.y * 128;
    const int lr = lane & 15;
    const int lq = lane >> 4;

    f32x4 acc[2][4];
#pragma unroll
    for (int i = 0; i < 2; i++)
#pragma unroll
        for (int j = 0; j < 4; j++) acc[i][j] = f32x4{0.f, 0.f, 0.f, 0.f};

    for (int k0 = 0; k0 < CDIM; k0 += 64) {
#pragma unroll
        for (int s = 0; s < 2; s++) {
            int i = tid + s * 256;
            int kk = i >> 8, rr = (i >> 2) & 63, cc = i & 3;
            gld16(&A[(size_t)(row0 + rr) * CDIM + k0 + kk * 32 + cc * 8], &Al[i * 8]);
        }
#pragma unroll
        for (int s = 0; s < 4; s++) {
            int i = tid + s * 256;
            int kk = i >> 9, rr = (i >> 2) & 127, cc = i & 3;
            gld16(&Bt[(size_t)(col0 + rr) * CDIM + k0 + kk * 32 + cc * 8], &Bl[i * 8]);
        }
        __syncthreads();
#pragma unroll
        for (int kk = 0; kk < 2; kk++) {
            bf16x8 af[2], bfr[4];
#pragma unroll
            for (int t = 0; t < 2; t++)
                af[t] = *reinterpret_cast<const bf16x8*>(&Al[kk * 2048 + (wm + t * 16 + lr) * 32 + lq * 8]);
#pragma unroll
            for (int t = 0; t < 4; t++)
                bfr[t] = *reinterpret_cast<const bf16x8*>(&Bl[kk * 4096 + (wn + t * 16 + lr) * 32 + lq * 8]);
#pragma unroll
            for (int mt = 0; mt < 2; mt++)
#pragma unroll
                for (int nt = 0; nt < 4; nt++)
                    acc[mt][nt] = __builtin_amdgcn_mfma_f32_16x16x32_bf16(af[mt], bfr[nt], acc[mt][nt], 0, 0, 0);
        }
        __syncthreads();
    }
#pragma unroll
    for (int mt = 0; mt < 2; mt++) {
#pragma unroll
        for (int nt = 0; nt < 4; nt++) {
            int col = col0 + wn + nt * 16 + lr;
            float bv = bias[col];
#pragma unroll
            for (int r = 0; r < 4; r++) {
                int row = row0 + wm + mt * 16 + lq * 4 + r;
                C[(size_t)row * CDIM + col] = acc[mt][nt][r] + bv;
            }
        }
    }
}

// ---------------- flash attention: split-q for occupancy (1 q-tile/wave, 512 blocks) ----------------
// Round-9 change: grid 256->512 blocks (2 blocks/CU = 2 waves/SIMD) so one wave's softmax
// VALU phase overlaps the other's MFMA phase; V-frag loads hoisted ahead of QK^T; 4-way
// split of the l-sum fadd chain; setprio around MFMA clusters (T5).
__global__ __launch_bounds__(256, 2) void attn_kernel(const u16* __restrict__ Qf,
                                                      const u16* __restrict__ Kf,
                                                      const u16* __restrict__ Vf,
                                                      u16* __restrict__ AO) {
    const int id = blockIdx.x;            // 512 blocks; blocks of one (b,h) share id%8 -> same XCD
    const int bh = id & 31;
    const int qb = id >> 5;               // [0,16)
    const int b = bh >> 4, h = bh & 15;
    const int tid = threadIdx.x, lane = tid & 63, wave = tid >> 6;
    const int l31 = lane & 31, l5 = lane >> 5;
    const int qt = qb * 4 + wave;         // this wave's single 32-q tile, [0,64)

    // Q B-frags (c2-prescaled), frag-ordered, coalesced
    bf16x8 qa[4];
    {
        const u16* qp = Qf + ((size_t)(bh * 64 + qt) * 4) * 512 + lane * 8;
#pragma unroll
        for (int kc = 0; kc < 4; kc++)
            qa[kc] = *reinterpret_cast<const bf16x8*>(qp + kc * 512);
    }
    f32x16 o0, o1, zc;
#pragma unroll
    for (int i = 0; i < 16; i++) { o0[i] = 0.f; o1[i] = 0.f; zc[i] = 0.f; }
    float lacc[4];
#pragma unroll
    for (int i = 0; i < 4; i++) lacc[i] = 0.f;

    const u16* kcur = Kf + (size_t)bh * 32 * 4096 + lane * 8;
    const u16* vcur = Vf + (size_t)bh * 32 * 4096 + lane * 8;

    bf16x8 ka[8];
#pragma unroll
    for (int i = 0; i < 8; i++) ka[i] = *reinterpret_cast<const bf16x8*>(kcur + i * 512);

    for (int kb = 0; kb < 32; kb++) {
        // V-frags issued FIRST: load latency hides under the QK^T MFMA cluster
        bf16x8 vfr[8];
#pragma unroll
        for (int i = 0; i < 8; i++) vfr[i] = *reinterpret_cast<const bf16x8*>(vcur + i * 512);
        // S^T = K * Q^T
        f32x16 st0, st1;
        __builtin_amdgcn_s_setprio(1);
        st0 = __builtin_amdgcn_mfma_f32_32x32x16_bf16(ka[0], qa[0], zc, 0, 0, 0);
        st1 = __builtin_amdgcn_mfma_f32_32x32x16_bf16(ka[1], qa[0], zc, 0, 0, 0);
#pragma unroll
        for (int kc = 1; kc < 4; kc++) {
            st0 = __builtin_amdgcn_mfma_f32_32x32x16_bf16(ka[kc * 2],     qa[kc], st0, 0, 0, 0);
            st1 = __builtin_amdgcn_mfma_f32_32x32x16_bf16(ka[kc * 2 + 1], qa[kc], st1, 0, 0, 0);
        }
        __builtin_amdgcn_s_setprio(0);
        // prefetch next tile's K in place; latency hides under softmax
        const u16* knext = kcur + (kb < 31 ? 4096 : 0);
#pragma unroll
        for (int i = 0; i < 8; i++) ka[i] = *reinterpret_cast<const bf16x8*>(knext + i * 512);
        kcur = knext;
        vcur += 4096;
        // softmax: P = exp2(st) (prescaled; |st| < ~9, in range)
        bf16x8 pa[4];
        {
            float pe[16];
            union { bf16x8 v; u32 w[4]; } ua, ub;
#pragma unroll
            for (int r = 0; r < 16; r++) { pe[r] = __builtin_amdgcn_exp2f(st0[r]); lacc[r & 3] += pe[r]; }
#pragma unroll
            for (int j = 0; j < 4; j++) { ua.w[j] = pkbf(pe[2 * j], pe[2 * j + 1]); ub.w[j] = pkbf(pe[8 + 2 * j], pe[8 + 2 * j + 1]); }
            pa[0] = ua.v; pa[1] = ub.v;
#pragma unroll
            for (int r = 0; r < 16; r++) { pe[r] = __builtin_amdgcn_exp2f(st1[r]); lacc[r & 3] += pe[r]; }
#pragma unroll
            for (int j = 0; j < 4; j++) { ua.w[j] = pkbf(pe[2 * j], pe[2 * j + 1]); ub.w[j] = pkbf(pe[8 + 2 * j], pe[8 + 2 * j + 1]); }
            pa[2] = ua.v; pa[3] = ub.v;
        }
        // O += P V (V rows pre-permuted to match P's register key order)
        __builtin_amdgcn_s_setprio(1);
#pragma unroll
        for (int c = 0; c < 4; c++) {
            o0 = __builtin_amdgcn_mfma_f32_32x32x16_bf16(pa[c], vfr[c * 2],     o0, 0, 0, 0);
            o1 = __builtin_amdgcn_mfma_f32_32x32x16_bf16(pa[c], vfr[c * 2 + 1], o1, 0, 0, 0);
        }
        __builtin_amdgcn_s_setprio(0);
    }
    // epilogue
    {
        float l = (lacc[0] + lacc[1]) + (lacc[2] + lacc[3]);
        l += __shfl_xor(l, 32);
        float linv = 1.0f / l;
        int q0 = qt * 32;
#pragma unroll
        for (int reg = 0; reg < 16; reg++) {
            int qrow = (reg & 3) + 8 * (reg >> 2) + 4 * l5;
            float li = __shfl(linv, qrow);
            AO[(size_t)(b * TSEQ + q0 + qrow) * CDIM + h * 64 + l31]      = f2bf(o0[reg] * li);
            AO[(size_t)(b * TSEQ + q0 + qrow) * CDIM + h * 64 + 32 + l31] = f2bf(o1[reg] * li);
        }
    }
}

extern "C" void kernel_launch(void* const* d_in, const int* in_sizes, int n_in,
                              void* d_out, int out_size, void* d_ws, size_t ws_size,
                              hipStream_t stream) {
    const float* x      = (const float*)d_in[0];
    const float* w_qkv  = (const float*)d_in[1];
    const float* b_qkv  = (const float*)d_in[2];
    const float* w_proj = (const float*)d_in[3];
    const float* b_proj = (const float*)d_in[4];
    float* out = (float*)d_out;

    u16* ws     = (u16*)d_ws;
    u16* Xb     = ws;                       // 4096x1024
    u16* Wqkvt  = Xb + 4194304;             // 3072x1024
    u16* Wprojt = Wqkvt + 3145728;          // 1024x1024
    u16* Qf     = Wprojt + 1048576;         // frag-ordered Q (c2-prescaled), 8 MB
    u16* Kf     = Qf + 4194304;             // frag-ordered K tiles, 8 MB
    u16* Vf     = Kf + 4194304;             // frag-ordered + PV-permuted V tiles, 8 MB
    u16* AO     = Vf + 4194304;             // 4096x1024
    // total ~50.3 MB

    prep_kernel<<<8192, 256, 0, stream>>>(x, w_qkv, w_proj, Xb, Wqkvt, Wprojt);
    gemm_qkv<<<dim3(32, 24), 256, 0, stream>>>(Xb, Wqkvt, b_qkv, Qf, Kf, Vf);
    attn_kernel<<<512, 256, 0, stream>>>(Qf, Kf, Vf, AO);
    gemm_proj<<<dim3(64, 8), 256, 0, stream>>>(AO, Wprojt, b_proj, out);
}

// Round 2
// 172.590 us; speedup vs baseline: 1.0492x; 1.0492x over previous
//
#include <hip/hip_runtime.h>

typedef unsigned short u16;
typedef unsigned int   u32;
typedef __bf16 bf16x8 __attribute__((ext_vector_type(8)));
typedef float  f32x4  __attribute__((ext_vector_type(4)));
typedef float  f32x16 __attribute__((ext_vector_type(16)));

#define TSEQ 2048
#define NHEAD 16
#define HDIM 64
#define CDIM 1024
#define N3   3072
#define MROWS 4096

__device__ __forceinline__ u16 f2bf(float f) {
    union { float f; u32 u; } v; v.f = f;
    u32 r = v.u + 0x7FFFu + ((v.u >> 16) & 1u);
    return (u16)(r >> 16);
}

// pack two fp32 -> packed bf16, 1-2 VALU ops.
__device__ __forceinline__ u32 pkbf(float a, float b) {
#if __has_builtin(__builtin_amdgcn_cvt_pk_bf16_f32)
    typedef __bf16 bf16x2 __attribute__((ext_vector_type(2)));
    bf16x2 t = __builtin_amdgcn_cvt_pk_bf16_f32(a, b);
    union { bf16x2 v; u32 u; } c; c.v = t; return c.u;
#else
    union { float f; u32 u; } ua, ub; ua.f = a; ub.f = b;
    u32 sel = 0x07060302, d;
    asm("v_perm_b32 %0, %1, %2, %3" : "=v"(d) : "v"(ub.u), "v"(ua.u), "v"(sel));
    return d;
#endif
}

// async global->LDS, 16B per lane (m97; GEMM staging only)
__device__ __forceinline__ void gld16(const u16* g, u16* l) {
    __builtin_amdgcn_global_load_lds(
        (const __attribute__((address_space(1))) u32*)g,
        (__attribute__((address_space(3))) u32*)l, 16, 0, 0);
}

// ---------------- merged prep: x->bf16 pack  +  both weight transposes ----------------
__global__ __launch_bounds__(256) void prep_kernel(const float* __restrict__ x,
                                                   const float* __restrict__ wqkv,
                                                   const float* __restrict__ wproj,
                                                   u16* __restrict__ Xb,
                                                   u16* __restrict__ oqkv, u16* __restrict__ oproj) {
    __shared__ float tile[32][33];
    const int bx = blockIdx.x;
    const int tid = threadIdx.x;
    if (bx < 4096) {  // pack region
        int i = bx * 256 + tid;
        float4 v = reinterpret_cast<const float4*>(x)[i];
        ushort4 o;
        o.x = f2bf(v.x); o.y = f2bf(v.y); o.z = f2bf(v.z); o.w = f2bf(v.w);
        reinterpret_cast<ushort4*>(Xb)[i] = o;
        return;
    }
    int idx = bx - 4096;
    int bnx = idx & 127;
    int k0  = (idx >> 7) * 32;
    const float* in; u16* out; int N, n0;
    if (bnx < 96) { in = wqkv;  out = oqkv;  N = 3072; n0 = bnx * 32; }
    else          { in = wproj; out = oproj; N = 1024; n0 = (bnx - 96) * 32; }
    int tx = tid & 31, ty = tid >> 5;  // (32, 8)
#pragma unroll
    for (int i = 0; i < 4; i++)
        tile[ty + i * 8][tx] = in[(size_t)(k0 + ty + i * 8) * N + n0 + tx];
    __syncthreads();
#pragma unroll
    for (int i = 0; i < 4; i++)
        out[(size_t)(n0 + ty + i * 8) * 1024 + k0 + tx] = f2bf(tile[tx][ty + i * 8]);
}

// ---------------- QKV GEMM: frag-order epilogue via LDS bounce (verified rounds 7/8) ----------------
// Qf chunk ((bh*64+qt)*4+kc): [lane=l5*32+q31][j] = Q[qt*32+q31][kc*16+l5*8+j]*c2
// Kf tile (bh*32+kb), chunk kc*2+nt: [lane][j] = K[nt*32+l31][kc*16+l5*8+j]
// Vf tile (bh*32+kb), chunk c*2+dt:  [lane][j] = V[c*16+(j>>2)*8+l5*4+(j&3)][dt*32+l31]
__global__ __launch_bounds__(256) void gemm_qkv(const u16* __restrict__ A, const u16* __restrict__ Bt,
                                                const float* __restrict__ bias, u16* __restrict__ Qf,
                                                u16* __restrict__ Kf, u16* __restrict__ Vf) {
    __shared__ __align__(16) u16 Al[128 * 32];
    __shared__ __align__(16) u16 Bl[128 * 32];
    __shared__ __align__(16) u16 Im[16384];
    const int tid  = threadIdx.x;
    const int lane = tid & 63;
    const int wave = tid >> 6;
    const int wm = (wave >> 1) * 64;
    const int wn = (wave & 1) * 64;
    const int row0 = blockIdx.x * 128;
    const int col0 = blockIdx.y * 128;
    const int lr = lane & 15;
    const int lq = lane >> 4;
    const float c2 = 0.125f * 1.44269504088896f;

    f32x4 acc[4][4];
#pragma unroll
    for (int i = 0; i < 4; i++)
#pragma unroll
        for (int j = 0; j < 4; j++) acc[i][j] = f32x4{0.f, 0.f, 0.f, 0.f};

    const int sr = tid >> 2, sc_ = (tid & 3) * 8;

    for (int k0 = 0; k0 < CDIM; k0 += 32) {
#pragma unroll
        for (int s = 0; s < 2; s++) {
            int i = tid + s * 256;
            int r = sr + s * 64;
            gld16(&A[(size_t)(row0 + r) * CDIM + k0 + sc_], &Al[i * 8]);
            gld16(&Bt[(size_t)(col0 + r) * CDIM + k0 + sc_], &Bl[i * 8]);
        }
        __syncthreads();
        bf16x8 af[4], bfr[4];
#pragma unroll
        for (int t = 0; t < 4; t++) {
            af[t]  = *reinterpret_cast<const bf16x8*>(&Al[(wm + t * 16 + lr) * 32 + lq * 8]);
            bfr[t] = *reinterpret_cast<const bf16x8*>(&Bl[(wn + t * 16 + lr) * 32 + lq * 8]);
        }
#pragma unroll
        for (int mt = 0; mt < 4; mt++)
#pragma unroll
            for (int nt = 0; nt < 4; nt++)
                acc[mt][nt] = __builtin_amdgcn_mfma_f32_16x16x32_bf16(af[mt], bfr[nt], acc[mt][nt], 0, 0, 0);
        __syncthreads();
    }

    const int region = col0 >> 10;
    const int h_base = (col0 & 1023) >> 6;
#pragma unroll
    for (int mt = 0; mt < 4; mt++) {
#pragma unroll
        for (int nt = 0; nt < 4; nt++) {
            int n_local = wn + nt * 16 + lr;
            float bv = bias[col0 + n_local];
            int h_local = n_local >> 6;
            int d = n_local & 63;
#pragma unroll
            for (int r = 0; r < 4; r++) {
                int m_local = wm + mt * 16 + lq * 4 + r;
                float v = acc[mt][nt][r] + bv;
                if (region == 0) {
                    int qt_local = m_local >> 5, q31 = m_local & 31;
                    int kc = d >> 4, l5b = (d >> 3) & 1, j = d & 7;
                    int lc = (h_local * 4 + qt_local) * 4 + kc;
                    Im[lc * 512 + (l5b * 32 + q31) * 8 + j] = f2bf(v * c2);
                } else if (region == 1) {
                    int kb_local = m_local >> 6, tr = m_local & 63;
                    int kc = d >> 4, l5b = (d >> 3) & 1, j = d & 7;
                    int nt2 = tr >> 5, p31 = tr & 31;
                    int lc = (h_local * 2 + kb_local) * 8 + kc * 2 + nt2;
                    Im[lc * 512 + (l5b * 32 + p31) * 8 + j] = f2bf(v);
                } else {
                    int kb_local = m_local >> 6, tr = m_local & 63;
                    int cV = tr >> 4, dt2 = d >> 5, p31 = d & 31;
                    int l5b = (tr >> 2) & 1;
                    int j = ((tr >> 3) & 1) * 4 + (tr & 3);
                    int lc = (h_local * 2 + kb_local) * 8 + cV * 2 + dt2;
                    Im[lc * 512 + (l5b * 32 + p31) * 8 + j] = f2bf(v);
                }
            }
        }
    }
    __syncthreads();
    const int bq = row0 >> 11;
    const int qrow0 = row0 & 2047;
#pragma unroll
    for (int s = 0; s < 8; s++) {
        int slot = s * 256 + tid;
        int lc = slot >> 6, li = slot & 63;
        uint4 data = *reinterpret_cast<const uint4*>(&Im[slot * 8]);
        if (region == 0) {
            int h_local = lc >> 4, qt_local = (lc >> 2) & 3, kc = lc & 3;
            size_t off = ((size_t)((bq * 16 + h_base + h_local) * 64 + (qrow0 >> 5) + qt_local) * 4 + kc) * 512
                       + li * 8;
            *reinterpret_cast<uint4*>(Qf + off) = data;
        } else {
            int h_local = lc >> 4, kb_local = (lc >> 3) & 1, cit = lc & 7;
            size_t off = (size_t)((bq * 16 + h_base + h_local) * 32 + (qrow0 >> 6) + kb_local) * 4096
                       + cit * 512 + li * 8;
            *reinterpret_cast<uint4*>((region == 1 ? Kf : Vf) + off) = data;
        }
    }
}

// ---------------- proj GEMM: 64x128 tile, BK=64 (2x BK=32 sub-tiles), fp32 out ----------------
__global__ __launch_bounds__(256) void gemm_proj(const u16* __restrict__ A, const u16* __restrict__ Bt,
                                                 const float* __restrict__ bias, float* __restrict__ C) {
    __shared__ __align__(16) u16 Al[2 * 64 * 32];    // [kk][64][32]
    __shared__ __align__(16) u16 Bl[2 * 128 * 32];   // [kk][128][32]
    const int tid  = threadIdx.x;
    const int lane = tid & 63;
    const int wave = tid >> 6;
    const int wm = (wave >> 1) * 32;
    const int wn = (wave & 1) * 64;
    const int row0 = blockIdx.x * 64;
    const int col0 = blockIdx.y * 128;
    const int lr = lane & 15;
    const int lq = lane >> 4;

    f32x4 acc[2][4];
#pragma unroll
    for (int i = 0; i < 2; i++)
#pragma unroll
        for (int j = 0; j < 4; j++) acc[i][j] = f32x4{0.f, 0.f, 0.f, 0.f};

    for (int k0 = 0; k0 < CDIM; k0 += 64) {
#pragma unroll
        for (int s = 0; s < 2; s++) {
            int i = tid + s * 256;
            int kk = i >> 8, rr = (i >> 2) & 63, cc = i & 3;
            gld16(&A[(size_t)(row0 + rr) * CDIM + k0 + kk * 32 + cc * 8], &Al[i * 8]);
        }
#pragma unroll
        for (int s = 0; s < 4; s++) {
            int i = tid + s * 256;
            int kk = i >> 9, rr = (i >> 2) & 127, cc = i & 3;
            gld16(&Bt[(size_t)(col0 + rr) * CDIM + k0 + kk * 32 + cc * 8], &Bl[i * 8]);
        }
        __syncthreads();
#pragma unroll
        for (int kk = 0; kk < 2; kk++) {
            bf16x8 af[2], bfr[4];
#pragma unroll
            for (int t = 0; t < 2; t++)
                af[t] = *reinterpret_cast<const bf16x8*>(&Al[kk * 2048 + (wm + t * 16 + lr) * 32 + lq * 8]);
#pragma unroll
            for (int t = 0; t < 4; t++)
                bfr[t] = *reinterpret_cast<const bf16x8*>(&Bl[kk * 4096 + (wn + t * 16 + lr) * 32 + lq * 8]);
#pragma unroll
            for (int mt = 0; mt < 2; mt++)
#pragma unroll
                for (int nt = 0; nt < 4; nt++)
                    acc[mt][nt] = __builtin_amdgcn_mfma_f32_16x16x32_bf16(af[mt], bfr[nt], acc[mt][nt], 0, 0, 0);
        }
        __syncthreads();
    }
#pragma unroll
    for (int mt = 0; mt < 2; mt++) {
#pragma unroll
        for (int nt = 0; nt < 4; nt++) {
            int col = col0 + wn + nt * 16 + lr;
            float bv = bias[col];
#pragma unroll
            for (int r = 0; r < 4; r++) {
                int row = row0 + wm + mt * 16 + lq * 4 + r;
                C[(size_t)row * CDIM + col] = acc[mt][nt][r] + bv;
            }
        }
    }
}

// ---------------- flash attention: round-0 structure + 1-kb-ahead QK^T software pipeline ----------------
// Round-2: back to 256 blocks / 2 q-tiles per wave (4 independent MFMA chains, 1 block/CU).
// New: QK^T(kb+1) is computed in the same basic block as softmax(kb) (2-deep st buffer,
// static names via kb-unroll-by-2) so the scheduler can interleave the MFMA cluster with
// the exp2/pack VALU — T15 mechanism. Register growth is free at 1 wave/SIMD.
// l-sum fadd chain split 4-ways per tile.
#define SUBITER(KB, SP00, SP01, SP10, SP11, SN00, SN01, SN10, SN11)                                  \
  {                                                                                                  \
    bf16x8 vfr[8];                                                                                   \
    _Pragma("unroll") for (int i = 0; i < 8; i++)                                                    \
        vfr[i] = *reinterpret_cast<const bf16x8*>(vcur + i * 512);                                   \
    vcur += 4096;                                                                                    \
    /* QK^T(kb+1) into SN — independent of softmax(SP) below */                                      \
    SN00 = __builtin_amdgcn_mfma_f32_32x32x16_bf16(ka[0], qa0[0], zc, 0, 0, 0);                      \
    SN01 = __builtin_amdgcn_mfma_f32_32x32x16_bf16(ka[1], qa0[0], zc, 0, 0, 0);                      \
    SN10 = __builtin_amdgcn_mfma_f32_32x32x16_bf16(ka[0], qa1[0], zc, 0, 0, 0);                      \
    SN11 = __builtin_amdgcn_mfma_f32_32x32x16_bf16(ka[1], qa1[0], zc, 0, 0, 0);                      \
    _Pragma("unroll") for (int kc = 1; kc < 4; kc++) {                                               \
      SN00 = __builtin_amdgcn_mfma_f32_32x32x16_bf16(ka[kc * 2],     qa0[kc], SN00, 0, 0, 0);        \
      SN01 = __builtin_amdgcn_mfma_f32_32x32x16_bf16(ka[kc * 2 + 1], qa0[kc], SN01, 0, 0, 0);        \
      SN10 = __builtin_amdgcn_mfma_f32_32x32x16_bf16(ka[kc * 2],     qa1[kc], SN10, 0, 0, 0);        \
      SN11 = __builtin_amdgcn_mfma_f32_32x32x16_bf16(ka[kc * 2 + 1], qa1[kc], SN11, 0, 0, 0);        \
    }                                                                                                \
    /* softmax(kb): P = exp2(SP) (prescaled; in range) */                                            \
    bf16x8 pa0[4], pa1[4];                                                                           \
    {                                                                                                \
      float pe[16];                                                                                  \
      union { bf16x8 v; u32 w[4]; } ua, ub;                                                          \
      _Pragma("unroll") for (int r = 0; r < 16; r++) {                                               \
        pe[r] = __builtin_amdgcn_exp2f(SP00[r]); la0[r & 3] += pe[r]; }                              \
      _Pragma("unroll") for (int j = 0; j < 4; j++) {                                                \
        ua.w[j] = pkbf(pe[2 * j], pe[2 * j + 1]); ub.w[j] = pkbf(pe[8 + 2 * j], pe[8 + 2 * j + 1]); }\
      pa0[0] = ua.v; pa0[1] = ub.v;                                                                  \
      _Pragma("unroll") for (int r = 0; r < 16; r++) {                                               \
        pe[r] = __builtin_amdgcn_exp2f(SP01[r]); la0[r & 3] += pe[r]; }                              \
      _Pragma("unroll") for (int j = 0; j < 4; j++) {                                                \
        ua.w[j] = pkbf(pe[2 * j], pe[2 * j + 1]); ub.w[j] = pkbf(pe[8 + 2 * j], pe[8 + 2 * j + 1]); }\
      pa0[2] = ua.v; pa0[3] = ub.v;                                                                  \
      _Pragma("unroll") for (int r = 0; r < 16; r++) {                                               \
        pe[r] = __builtin_amdgcn_exp2f(SP10[r]); la1[r & 3] += pe[r]; }                              \
      _Pragma("unroll") for (int j = 0; j < 4; j++) {                                                \
        ua.w[j] = pkbf(pe[2 * j], pe[2 * j + 1]); ub.w[j] = pkbf(pe[8 + 2 * j], pe[8 + 2 * j + 1]); }\
      pa1[0] = ua.v; pa1[1] = ub.v;                                                                  \
      _Pragma("unroll") for (int r = 0; r < 16; r++) {                                               \
        pe[r] = __builtin_amdgcn_exp2f(SP11[r]); la1[r & 3] += pe[r]; }                              \
      _Pragma("unroll") for (int j = 0; j < 4; j++) {                                                \
        ua.w[j] = pkbf(pe[2 * j], pe[2 * j + 1]); ub.w[j] = pkbf(pe[8 + 2 * j], pe[8 + 2 * j + 1]); }\
      pa1[2] = ua.v; pa1[3] = ub.v;                                                                  \
    }                                                                                                \
    /* K(kb+2) prefetch; distance to use = PV + next V-loads */                                      \
    {                                                                                                \
      int knext = (KB) + 2; if (knext > 31) knext = 31;                                              \
      const u16* kp = kbase + (size_t)knext * 4096;                                                  \
      _Pragma("unroll") for (int i = 0; i < 8; i++)                                                  \
        ka[i] = *reinterpret_cast<const bf16x8*>(kp + i * 512);                                      \
    }                                                                                                \
    /* O += P V */                                                                                   \
    _Pragma("unroll") for (int c = 0; c < 4; c++) {                                                  \
      o00 = __builtin_amdgcn_mfma_f32_32x32x16_bf16(pa0[c], vfr[c * 2],     o00, 0, 0, 0);           \
      o01 = __builtin_amdgcn_mfma_f32_32x32x16_bf16(pa0[c], vfr[c * 2 + 1], o01, 0, 0, 0);           \
      o10 = __builtin_amdgcn_mfma_f32_32x32x16_bf16(pa1[c], vfr[c * 2],     o10, 0, 0, 0);           \
      o11 = __builtin_amdgcn_mfma_f32_32x32x16_bf16(pa1[c], vfr[c * 2 + 1], o11, 0, 0, 0);           \
    }                                                                                                \
  }

__global__ __launch_bounds__(256, 1) void attn_kernel(const u16* __restrict__ Qf,
                                                      const u16* __restrict__ Kf,
                                                      const u16* __restrict__ Vf,
                                                      u16* __restrict__ AO) {
    const int id = blockIdx.x;            // 256 blocks; blocks of one (b,h) share id%8 -> same XCD
    const int bh = id & 31;
    const int qb = id >> 5;               // [0,8)
    const int b = bh >> 4, h = bh & 15;
    const int tid = threadIdx.x, lane = tid & 63, wave = tid >> 6;
    const int l31 = lane & 31, l5 = lane >> 5;
    const int qt0 = qb * 8 + wave * 2;    // this wave's two 32-q tiles

    // Q B-frags (c2-prescaled), frag-ordered, coalesced
    bf16x8 qa0[4], qa1[4];
    {
        const u16* qp = Qf + ((size_t)(bh * 64 + qt0) * 4) * 512 + lane * 8;
#pragma unroll
        for (int kc = 0; kc < 4; kc++) {
            qa0[kc] = *reinterpret_cast<const bf16x8*>(qp + kc * 512);
            qa1[kc] = *reinterpret_cast<const bf16x8*>(qp + 2048 + kc * 512);
        }
    }
    f32x16 o00, o01, o10, o11, zc;
#pragma unroll
    for (int i = 0; i < 16; i++) { o00[i] = 0.f; o01[i] = 0.f; o10[i] = 0.f; o11[i] = 0.f; zc[i] = 0.f; }
    float la0[4], la1[4];
#pragma unroll
    for (int i = 0; i < 4; i++) { la0[i] = 0.f; la1[i] = 0.f; }

    const u16* kbase = Kf + (size_t)bh * 32 * 4096 + lane * 8;
    const u16* vcur  = Vf + (size_t)bh * 32 * 4096 + lane * 8;

    bf16x8 ka[8];
#pragma unroll
    for (int i = 0; i < 8; i++) ka[i] = *reinterpret_cast<const bf16x8*>(kbase + i * 512);

    // prologue: st(kb=0) for both tiles
    f32x16 sA0, sA1, sA2, sA3, sB0, sB1, sB2, sB3;
    sA0 = __builtin_amdgcn_mfma_f32_32x32x16_bf16(ka[0], qa0[0], zc, 0, 0, 0);
    sA1 = __builtin_amdgcn_mfma_f32_32x32x16_bf16(ka[1], qa0[0], zc, 0, 0, 0);
    sA2 = __builtin_amdgcn_mfma_f32_32x32x16_bf16(ka[0], qa1[0], zc, 0, 0, 0);
    sA3 = __builtin_amdgcn_mfma_f32_32x32x16_bf16(ka[1], qa1[0], zc, 0, 0, 0);
#pragma unroll
    for (int kc = 1; kc < 4; kc++) {
        sA0 = __builtin_amdgcn_mfma_f32_32x32x16_bf16(ka[kc * 2],     qa0[kc], sA0, 0, 0, 0);
        sA1 = __builtin_amdgcn_mfma_f32_32x32x16_bf16(ka[kc * 2 + 1], qa0[kc], sA1, 0, 0, 0);
        sA2 = __builtin_amdgcn_mfma_f32_32x32x16_bf16(ka[kc * 2],     qa1[kc], sA2, 0, 0, 0);
        sA3 = __builtin_amdgcn_mfma_f32_32x32x16_bf16(ka[kc * 2 + 1], qa1[kc], sA3, 0, 0, 0);
    }
    // ka <- K(1) for the first pipelined QK^T
#pragma unroll
    for (int i = 0; i < 8; i++) ka[i] = *reinterpret_cast<const bf16x8*>(kbase + 4096 + i * 512);

    for (int kb2 = 0; kb2 < 16; kb2++) {
        int kb = kb2 * 2;
        SUBITER(kb,     sA0, sA1, sA2, sA3, sB0, sB1, sB2, sB3);
        SUBITER(kb + 1, sB0, sB1, sB2, sB3, sA0, sA1, sA2, sA3);
    }

    // epilogue, tile 0 then tile 1
    {
        float l = (la0[0] + la0[1]) + (la0[2] + la0[3]);
        l += __shfl_xor(l, 32);
        float linv = 1.0f / l;
        int q0 = qt0 * 32;
#pragma unroll
        for (int reg = 0; reg < 16; reg++) {
            int qrow = (reg & 3) + 8 * (reg >> 2) + 4 * l5;
            float li = __shfl(linv, qrow);
            AO[(size_t)(b * TSEQ + q0 + qrow) * CDIM + h * 64 + l31]      = f2bf(o00[reg] * li);
            AO[(size_t)(b * TSEQ + q0 + qrow) * CDIM + h * 64 + 32 + l31] = f2bf(o01[reg] * li);
        }
    }
    {
        float l = (la1[0] + la1[1]) + (la1[2] + la1[3]);
        l += __shfl_xor(l, 32);
        float linv = 1.0f / l;
        int q0 = (qt0 + 1) * 32;
#pragma unroll
        for (int reg = 0; reg < 16; reg++) {
            int qrow = (reg & 3) + 8 * (reg >> 2) + 4 * l5;
            float li = __shfl(linv, qrow);
            AO[(size_t)(b * TSEQ + q0 + qrow) * CDIM + h * 64 + l31]      = f2bf(o10[reg] * li);
            AO[(size_t)(b * TSEQ + q0 + qrow) * CDIM + h * 64 + 32 + l31] = f2bf(o11[reg] * li);
        }
    }
}

extern "C" void kernel_launch(void* const* d_in, const int* in_sizes, int n_in,
                              void* d_out, int out_size, void* d_ws, size_t ws_size,
                              hipStream_t stream) {
    const float* x      = (const float*)d_in[0];
    const float* w_qkv  = (const float*)d_in[1];
    const float* b_qkv  = (const float*)d_in[2];
    const float* w_proj = (const float*)d_in[3];
    const float* b_proj = (const float*)d_in[4];
    float* out = (float*)d_out;

    u16* ws     = (u16*)d_ws;
    u16* Xb     = ws;                       // 4096x1024
    u16* Wqkvt  = Xb + 4194304;             // 3072x1024
    u16* Wprojt = Wqkvt + 3145728;          // 1024x1024
    u16* Qf     = Wprojt + 1048576;         // frag-ordered Q (c2-prescaled), 8 MB
    u16* Kf     = Qf + 4194304;             // frag-ordered K tiles, 8 MB
    u16* Vf     = Kf + 4194304;             // frag-ordered + PV-permuted V tiles, 8 MB
    u16* AO     = Vf + 4194304;             // 4096x1024
    // total ~50.3 MB

    prep_kernel<<<8192, 256, 0, stream>>>(x, w_qkv, w_proj, Xb, Wqkvt, Wprojt);
    gemm_qkv<<<dim3(32, 24), 256, 0, stream>>>(Xb, Wqkvt, b_qkv, Qf, Kf, Vf);
    attn_kernel<<<256, 256, 0, stream>>>(Qf, Kf, Vf, AO);
    gemm_proj<<<dim3(64, 8), 256, 0, stream>>>(AO, Wprojt, b_proj, out);
}